// Round 7
// baseline (190.072 us; speedup 1.0000x reference)
//
#include <hip/hip_runtime.h>
#include <math.h>

namespace {

typedef float f32x4 __attribute__((ext_vector_type(4)));
typedef short s16x8 __attribute__((ext_vector_type(8)));

constexpr int C_   = 128;
constexpr int S_   = 16384;
constexpr int NTOK = 65536; // B*V*T*S

__device__ __forceinline__ unsigned short f2bf(float f) {
    unsigned int u = __float_as_uint(f);
    unsigned int r = (u + 0x7FFFu + ((u >> 16) & 1u)) >> 16;
    return (unsigned short)r;
}
__device__ __forceinline__ float bf2f(unsigned short h) {
    return __uint_as_float(((unsigned int)h) << 16);
}
// gelu tanh-approx; tanh via exp-form (identical math, v_exp_f32 based)
__device__ __forceinline__ float gelu_tanh(float v) {
    const float k0 = 0.7978845608028654f;
    float u = k0 * (v + 0.044715f * v * v * v);
    float au = fabsf(u);
    float E = __expf(2.0f * au);
    float th = 1.0f - 2.0f / (1.0f + E);       // tanh(|u|)
    th = (u < 0.f) ? -th : th;
    return 0.5f * v * (1.0f + th);
}

// ---------------------------------------------------------------------------
// Prep: pack weights into MFMA B-fragment order, bf16. (unchanged)
// ---------------------------------------------------------------------------
__global__ __launch_bounds__(256) void prep_weights(
    const float* __restrict__ Wq, const float* __restrict__ Wkv,
    const float* __restrict__ W_ao, const float* __restrict__ W1,
    const float* __restrict__ W2, const float* __restrict__ Wout,
    unsigned short* __restrict__ Wf)
{
    int idx = blockIdx.x * 256 + threadIdx.x;
    if (idx >= 147456) return;
    int seg, off, K, N; const float* src = nullptr;
    if (idx < 49152)       { seg = 0; off = 0;      K = 128; N = 384; }
    else if (idx < 65536)  { seg = 1; off = 49152;  K = 128; N = 128; src = W_ao; }
    else if (idx < 98304)  { seg = 2; off = 65536;  K = 128; N = 256; src = W1; }
    else if (idx < 131072) { seg = 3; off = 98304;  K = 256; N = 128; src = W2; }
    else                   { seg = 4; off = 131072; K = 128; N = 128; src = Wout; }
    int local = idx - off;
    int j    = local & 7;
    int lane = (local >> 3) & 63;
    int tl   = local >> 9;
    int KB   = K >> 5;
    int kb   = tl % KB;
    int nt   = tl / KB;
    int k    = kb * 32 + ((lane >> 4) << 3) + j;
    int col  = (nt << 4) + (lane & 15);
    float v;
    if (seg == 0) v = (col < 128) ? Wq[k * 128 + col] : Wkv[k * 256 + (col - 128)];
    else          v = src[k * N + col];
    Wf[idx] = f2bf(v);
}

// ---------------------------------------------------------------------------
// Kernel A: LN1 + [q | kv] projection.  M-tile = 64 tokens, 4 waves.
// q fp32 -> full d_out rows ; k, v bf16 -> separate ws buffers (256B rows).
// ---------------------------------------------------------------------------
__global__ __launch_bounds__(256, 2) void qkv_kernel(
    const float* __restrict__ x,
    const float* __restrict__ ln1_g, const float* __restrict__ ln1_b,
    const unsigned short* __restrict__ Wf,
    const float* __restrict__ b_kv,
    float* qout, unsigned short* __restrict__ kout,
    unsigned short* __restrict__ vout)
{
    __shared__ unsigned short xet[64 * 128]; // bf16, XOR-swizzled, 16KB
    const int tile = blockIdx.x;
    const int t = threadIdx.x;

    // ---- phase 1: LN1, write xe tile (bf16, swizzled) ----
    {
        const int row = t >> 2;       // 0..63
        const int q4  = t & 3;        // quarter of the row
        const int tok = tile * 64 + row;
        const float* xr = x + (size_t)tok * C_ + q4 * 32;
        float v[32];
        float s0 = 0.f, s1 = 0.f;
        #pragma unroll
        for (int i = 0; i < 32; i += 4) {
            float4 f = *(const float4*)(xr + i);
            v[i] = f.x; v[i+1] = f.y; v[i+2] = f.z; v[i+3] = f.w;
            s0 += f.x + f.y + f.z + f.w;
            s1 += f.x*f.x + f.y*f.y + f.z*f.z + f.w*f.w;
        }
        s0 += __shfl_xor(s0, 1, 64); s1 += __shfl_xor(s1, 1, 64);
        s0 += __shfl_xor(s0, 2, 64); s1 += __shfl_xor(s1, 2, 64);
        const float mean = s0 * (1.0f / C_);
        const float var  = s1 * (1.0f / C_) - mean * mean;
        const float inv  = rsqrtf(var + 1e-5f);
        #pragma unroll
        for (int jj = 0; jj < 4; ++jj) {
            unsigned short tmp[8];
            #pragma unroll
            for (int j = 0; j < 8; ++j) {
                int k = q4 * 32 + jj * 8 + j;
                tmp[j] = f2bf((v[jj*8 + j] - mean) * inv * ln1_g[k] + ln1_b[k]);
            }
            int byte = row * 256 + (q4 * 32 + jj * 8) * 2;
            byte ^= (row & 7) << 4;
            *(s16x8*)((char*)xet + byte) = *(const s16x8*)tmp;
        }
    }
    __syncthreads();

    // ---- phase 2: MFMA GEMM  (M=64 x K=128) @ (K=128 x N=384) ----
    const int w = t >> 6, l = t & 63;
    const int arow = (w << 4) + (l & 15);
    s16x8 af[4];
    #pragma unroll
    for (int kb = 0; kb < 4; ++kb) {
        int byte = arow * 256 + (kb * 32 + ((l >> 4) << 3)) * 2;
        byte ^= (arow & 7) << 4;
        af[kb] = *(const s16x8*)((const char*)xet + byte);
    }
    f32x4 acc[24];
    #pragma unroll
    for (int nt = 0; nt < 24; ++nt) acc[nt] = (f32x4){0.f, 0.f, 0.f, 0.f};
    #pragma unroll
    for (int nt = 0; nt < 24; ++nt) {
        #pragma unroll
        for (int kb = 0; kb < 4; ++kb) {
            s16x8 bf = *(const s16x8*)(Wf + (size_t)((nt * 4 + kb) * 64 + l) * 8);
            acc[nt] = __builtin_amdgcn_mfma_f32_16x16x32_bf16(af[kb], bf, acc[nt], 0, 0, 0);
        }
    }
    // ---- epilogue: q fp32 (full d_out rows) ; k, v bf16 (split buffers) ----
    const int r0 = (l >> 4) << 2;
    const int colb = l & 15;
    #pragma unroll
    for (int nt = 0; nt < 8; ++nt) {
        const int col = nt * 16 + colb;
        #pragma unroll
        for (int reg = 0; reg < 4; ++reg) {
            const size_t tokr = (size_t)tile * 64 + (w << 4) + r0 + reg;
            qout[tokr * 128 + col] = acc[nt][reg];
        }
    }
    #pragma unroll
    for (int i = 0; i < 8; ++i) {
        const int ch = i * 16 + colb;
        const float bk = b_kv[ch];
        const float bv = b_kv[ch + 128];
        #pragma unroll
        for (int reg = 0; reg < 4; ++reg) {
            const size_t tokr = (size_t)tile * 64 + (w << 4) + r0 + reg;
            kout[tokr * 128 + ch] = f2bf(acc[8 + i][reg] + bk);
            vout[tokr * 128 + ch] = f2bf(acc[16 + i][reg] + bv);
        }
    }
}

// ---------------------------------------------------------------------------
// Kernel B: attention, 8 lanes per token.  (unchanged from R6)
// ---------------------------------------------------------------------------
__global__ __launch_bounds__(256, 5) void attn_kernel(
    const int* __restrict__ adjc, const unsigned char* __restrict__ mask,
    const float* __restrict__ wnh,
    const float* __restrict__ qbuf,
    const unsigned short* __restrict__ kbuf,
    const unsigned short* __restrict__ vbuf,
    unsigned short* __restrict__ obuf)
{
    __shared__ unsigned int sidx[32][9];   // gathered row index | mask<<31

    const int d   = blockIdx.x;
    const int xcd = d & 7, dj = d >> 3;
    const int bid = (xcd >> 1) * 512 + dj * 2 + (xcd & 1);
    const size_t base = (size_t)bid * 32;
    const int s0  = (int)(base & (S_ - 1));
    const int bvt = (int)(base >> 14);
    const int t = threadIdx.x;

    for (int i = t; i < 288; i += 256) {
        int r = i / 9, n = i - r * 9;
        int nb = adjc[(s0 + r) * 9 + n];
        unsigned int gi = (unsigned int)(bvt * S_ + nb);
        sidx[r][n] = gi | (mask[gi] ? 0x80000000u : 0u);
    }
    __syncthreads();

    const int w = t >> 6, l = t & 63;
    const int g = l >> 3, j = l & 7;      // token-in-wave, channel-chunk
    const int r = w * 8 + g;
    const size_t tok = base + r;

    float q[16];
    {
        const float4* qp = (const float4*)(qbuf + tok * 128 + j * 16);
        #pragma unroll
        for (int i = 0; i < 4; ++i) {
            float4 f = qp[i];
            q[4*i] = f.x; q[4*i+1] = f.y; q[4*i+2] = f.z; q[4*i+3] = f.w;
        }
    }
    unsigned int gm[9];
    #pragma unroll
    for (int n = 0; n < 9; ++n) gm[n] = sidx[r][n];

    float sp[9];
    #pragma unroll
    for (int n = 0; n < 9; ++n) {
        const s16x8* kp = (const s16x8*)(kbuf +
            (size_t)(gm[n] & 0x7fffffffu) * 128 + j * 16);
        s16x8 k0 = kp[0], k1 = kp[1];
        float a = 0.f;
        #pragma unroll
        for (int i = 0; i < 8; ++i) a += q[i]     * bf2f((unsigned short)k0[i]);
        #pragma unroll
        for (int i = 0; i < 8; ++i) a += q[8 + i] * bf2f((unsigned short)k1[i]);
        sp[n] = a;
    }
    #pragma unroll
    for (int n = 0; n < 9; ++n) sp[n] += __shfl_xor(sp[n], 1, 64);

    float S[9];
    #pragma unroll
    for (int m = 0; m < 9; ++m) {
        float a = sp[m];   // identity part
        #pragma unroll
        for (int n = 0; n < 9; ++n) a += sp[n] * wnh[n * 9 + m];
        a *= 0.17677669529663687f;
        S[m] = (gm[m] & 0x80000000u) ? -1e9f : a;
    }
    float mx = S[0];
    #pragma unroll
    for (int m = 1; m < 9; ++m) mx = fmaxf(mx, S[m]);
    float e[9], se = 0.f;
    #pragma unroll
    for (int m = 0; m < 9; ++m) { e[m] = __expf(S[m] - mx); se += e[m]; }
    const float inv = 1.f / se;

    float ap[9];
    #pragma unroll
    for (int n = 0; n < 9; ++n) {
        float a = e[n];
        #pragma unroll
        for (int m = 0; m < 9; ++m) a += wnh[n * 9 + m] * e[m];
        ap[n] = a * inv;
    }

    float o[16];
    #pragma unroll
    for (int i = 0; i < 16; ++i) o[i] = 0.f;
    #pragma unroll
    for (int n = 0; n < 9; ++n) {
        const s16x8* vp = (const s16x8*)(vbuf +
            (size_t)(gm[n] & 0x7fffffffu) * 128 + j * 16);
        s16x8 v0 = vp[0], v1 = vp[1];
        const float a = ap[n];
        #pragma unroll
        for (int i = 0; i < 8; ++i) o[i]     += a * bf2f((unsigned short)v0[i]);
        #pragma unroll
        for (int i = 0; i < 8; ++i) o[8 + i] += a * bf2f((unsigned short)v1[i]);
    }
    unsigned short tmp[16];
    #pragma unroll
    for (int i = 0; i < 16; ++i) tmp[i] = f2bf(o[i]);
    s16x8* op = (s16x8*)(obuf + tok * 256 + j * 16);
    op[0] = *(const s16x8*)tmp;
    op[1] = *(const s16x8*)(tmp + 8);
}

// ---------------------------------------------------------------------------
// Kernel C: fused epilogue. Tile of 32 tokens, 2 waves, 2048 blocks.
// Wave w owns rows [w*16, w*16+16).  Same per-thread work as before; half
// the per-block critical path, 2x the block-level parallelism.
// ---------------------------------------------------------------------------
__global__ __launch_bounds__(128, 4) void mlp_kernel(
    const float* __restrict__ x,
    const unsigned short* obuf,
    const unsigned short* __restrict__ Wao_f, const unsigned short* __restrict__ W1f,
    const unsigned short* __restrict__ W2f, const unsigned short* __restrict__ Woutf,
    const float* __restrict__ ln2_g, const float* __restrict__ ln2_b,
    const float* __restrict__ b1, const float* __restrict__ b2,
    const float* __restrict__ gamma,
    float* outp)
{
    __shared__ unsigned short act[8192]; // 16KB activation tile (xm / h / y)
    const int tile = blockIdx.x;
    const int t = threadIdx.x;
    const int w = t >> 6, l = t & 63;
    const int arow = (w << 4) + (l & 15);         // A-frag local row (0..31)
    const int crow0 = (w << 4) + ((l >> 4) << 2); // C local row base
    const int colb = l & 15;
    const size_t base = (size_t)tile * 32;

    // ---- GEMM1: A = o (bf16 from d_out rows), B = W_ao ----
    s16x8 af[4];
    #pragma unroll
    for (int kb = 0; kb < 4; ++kb)
        af[kb] = *(const s16x8*)(obuf + (base + arow) * 256 + kb * 32 + ((l >> 4) << 3));
    f32x4 acc1[8];
    #pragma unroll
    for (int nt = 0; nt < 8; ++nt) acc1[nt] = (f32x4){0.f, 0.f, 0.f, 0.f};
    #pragma unroll
    for (int nt = 0; nt < 8; ++nt) {
        #pragma unroll
        for (int kb = 0; kb < 4; ++kb) {
            s16x8 bf = *(const s16x8*)(Wao_f + (size_t)((nt * 4 + kb) * 64 + l) * 8);
            acc1[nt] = __builtin_amdgcn_mfma_f32_16x16x32_bf16(af[kb], bf, acc1[nt], 0, 0, 0);
        }
    }

    // ---- x1 = x + ao ; LN2 row stats in-register ----
    float x1v[8][4];
    float ss[4] = {0.f, 0.f, 0.f, 0.f}, s2[4] = {0.f, 0.f, 0.f, 0.f};
    #pragma unroll
    for (int nt = 0; nt < 8; ++nt) {
        const int col = nt * 16 + colb;
        #pragma unroll
        for (int reg = 0; reg < 4; ++reg) {
            const size_t tokr = base + crow0 + reg;
            float xv = x[tokr * 128 + col] + acc1[nt][reg];
            x1v[nt][reg] = xv;
            ss[reg] += xv;
            s2[reg] += xv * xv;
        }
    }
    #pragma unroll
    for (int off = 1; off < 16; off <<= 1) {
        #pragma unroll
        for (int reg = 0; reg < 4; ++reg) {
            ss[reg] += __shfl_xor(ss[reg], off, 64);
            s2[reg] += __shfl_xor(s2[reg], off, 64);
        }
    }
    float mean[4], inv[4];
    #pragma unroll
    for (int reg = 0; reg < 4; ++reg) {
        mean[reg] = ss[reg] * (1.0f / 128.f);
        float var = s2[reg] * (1.0f / 128.f) - mean[reg] * mean[reg];
        inv[reg] = rsqrtf(var + 1e-5f);
    }
    // xm -> LDS (bf16, swizzled)
    #pragma unroll
    for (int nt = 0; nt < 8; ++nt) {
        const int col = nt * 16 + colb;
        const float lg = ln2_g[col], lb = ln2_b[col];
        #pragma unroll
        for (int reg = 0; reg < 4; ++reg) {
            const int lrow = crow0 + reg;
            float xm = (x1v[nt][reg] - mean[reg]) * inv[reg] * lg + lb;
            int byte = lrow * 256 + col * 2;
            byte ^= (lrow & 7) << 4;
            *(unsigned short*)((char*)act + byte) = f2bf(xm);
        }
    }
    __syncthreads();

    // ---- GEMM2: h = gelu(xm @ W1 + b1), N=256 ----
    #pragma unroll
    for (int kb = 0; kb < 4; ++kb) {
        int byte = arow * 256 + (kb * 32 + ((l >> 4) << 3)) * 2;
        byte ^= (arow & 7) << 4;
        af[kb] = *(const s16x8*)((const char*)act + byte);
    }
    f32x4 acc2[16];
    #pragma unroll
    for (int nt = 0; nt < 16; ++nt) acc2[nt] = (f32x4){0.f, 0.f, 0.f, 0.f};
    #pragma unroll
    for (int nt = 0; nt < 16; ++nt) {
        #pragma unroll
        for (int kb = 0; kb < 4; ++kb) {
            s16x8 bf = *(const s16x8*)(W1f + (size_t)((nt * 4 + kb) * 64 + l) * 8);
            acc2[nt] = __builtin_amdgcn_mfma_f32_16x16x32_bf16(af[kb], bf, acc2[nt], 0, 0, 0);
        }
    }
    __syncthreads();   // all xm reads done before overwriting act with h
    #pragma unroll
    for (int nt = 0; nt < 16; ++nt) {
        const int col2 = nt * 16 + colb;
        const float bb = b1[col2];
        #pragma unroll
        for (int reg = 0; reg < 4; ++reg) {
            const int lrow = crow0 + reg;
            float hv = gelu_tanh(acc2[nt][reg] + bb);
            int byte = lrow * 512 + col2 * 2;
            byte ^= (lrow & 7) << 4;
            *(unsigned short*)((char*)act + byte) = f2bf(hv);
        }
    }
    __syncthreads();

    // ---- GEMM3: z = h @ W2 (K=256) ; y = x1 + gamma*(z + b2) ----
    f32x4 acc3[8];
    #pragma unroll
    for (int nt = 0; nt < 8; ++nt) acc3[nt] = (f32x4){0.f, 0.f, 0.f, 0.f};
    #pragma unroll
    for (int kb = 0; kb < 8; ++kb) {
        int byte = arow * 512 + (kb * 32 + ((l >> 4) << 3)) * 2;
        byte ^= (arow & 7) << 4;
        s16x8 hf = *(const s16x8*)((const char*)act + byte);
        #pragma unroll
        for (int nt = 0; nt < 8; ++nt) {
            s16x8 bf = *(const s16x8*)(W2f + (size_t)((nt * 8 + kb) * 64 + l) * 8);
            acc3[nt] = __builtin_amdgcn_mfma_f32_16x16x32_bf16(hf, bf, acc3[nt], 0, 0, 0);
        }
    }
    __syncthreads();   // all h reads done before overwriting act with y
    #pragma unroll
    for (int nt = 0; nt < 8; ++nt) {
        const int col = nt * 16 + colb;
        const float gm = gamma[col], bb = b2[col];
        #pragma unroll
        for (int reg = 0; reg < 4; ++reg) {
            const int lrow = crow0 + reg;
            float y = x1v[nt][reg] + gm * (acc3[nt][reg] + bb);
            int byte = lrow * 256 + col * 2;
            byte ^= (lrow & 7) << 4;
            *(unsigned short*)((char*)act + byte) = f2bf(y);
        }
    }
    __syncthreads();

    // ---- GEMM4: out = y @ Wout ----
    #pragma unroll
    for (int kb = 0; kb < 4; ++kb) {
        int byte = arow * 256 + (kb * 32 + ((l >> 4) << 3)) * 2;
        byte ^= (arow & 7) << 4;
        af[kb] = *(const s16x8*)((const char*)act + byte);
    }
    f32x4 acc4[8];
    #pragma unroll
    for (int nt = 0; nt < 8; ++nt) acc4[nt] = (f32x4){0.f, 0.f, 0.f, 0.f};
    #pragma unroll
    for (int nt = 0; nt < 8; ++nt) {
        #pragma unroll
        for (int kb = 0; kb < 4; ++kb) {
            s16x8 bf = *(const s16x8*)(Woutf + (size_t)((nt * 4 + kb) * 64 + l) * 8);
            acc4[nt] = __builtin_amdgcn_mfma_f32_16x16x32_bf16(af[kb], bf, acc4[nt], 0, 0, 0);
        }
    }
    #pragma unroll
    for (int nt = 0; nt < 8; ++nt) {
        const int col = nt * 16 + colb;
        #pragma unroll
        for (int reg = 0; reg < 4; ++reg) {
            const size_t tokr = base + crow0 + reg;
            outp[tokr * 128 + col] = acc4[nt][reg];
        }
    }
}

} // namespace

extern "C" void kernel_launch(void* const* d_in, const int* in_sizes, int n_in,
                              void* d_out, int out_size, void* d_ws, size_t ws_size,
                              hipStream_t stream) {
    const float* x     = (const float*)d_in[0];
    const int*   adjc  = (const int*)d_in[1];
    const unsigned char* mask = (const unsigned char*)d_in[2];
    const float* ln1_g = (const float*)d_in[3];
    const float* ln1_b = (const float*)d_in[4];
    const float* Wq    = (const float*)d_in[5];
    const float* Wkv   = (const float*)d_in[6];
    const float* b_kv  = (const float*)d_in[7];
    const float* W_nh  = (const float*)d_in[8];
    const float* W_ao  = (const float*)d_in[9];
    const float* ln2_g = (const float*)d_in[10];
    const float* ln2_b = (const float*)d_in[11];
    const float* W1    = (const float*)d_in[12];
    const float* b1    = (const float*)d_in[13];
    const float* W2    = (const float*)d_in[14];
    const float* b2    = (const float*)d_in[15];
    const float* gamma = (const float*)d_in[16];
    const float* Wout  = (const float*)d_in[17];

    // ws layout: k bf16 [0,16MiB) ; v bf16 [16,32MiB) ; Wf fragments after.
    unsigned short* kbuf = (unsigned short*)d_ws;
    unsigned short* vbuf = kbuf + (size_t)NTOK * 128;
    unsigned short* Wf   = vbuf + (size_t)NTOK * 128;
    unsigned short* Wao_f  = Wf + 49152;
    unsigned short* W1f    = Wf + 65536;
    unsigned short* W2f    = Wf + 98304;
    unsigned short* Woutf  = Wf + 131072;

    float*          qbuf = (float*)d_out;           // q fp32 full rows
    unsigned short* obuf = (unsigned short*)d_out;  // o bf16 first 256B/row

    prep_weights<<<576, 256, 0, stream>>>(Wq, Wkv, W_ao, W1, W2, Wout, Wf);
    qkv_kernel<<<NTOK / 64, 256, 0, stream>>>(x, ln1_g, ln1_b, Wf, b_kv,
                                              qbuf, kbuf, vbuf);
    attn_kernel<<<NTOK / 32, 256, 0, stream>>>(adjc, mask, W_nh,
                                               qbuf, kbuf, vbuf, obuf);
    mlp_kernel<<<NTOK / 32, 128, 0, stream>>>(x, obuf, Wao_f, W1f, W2f, Woutf,
                                              ln2_g, ln2_b, b1, b2, gamma,
                                              (float*)d_out);
}

// Round 8
// 157.816 us; speedup vs baseline: 1.2044x; 1.2044x over previous
//
#include <hip/hip_runtime.h>
#include <math.h>

namespace {

typedef float f32x4 __attribute__((ext_vector_type(4)));
typedef short s16x8 __attribute__((ext_vector_type(8)));

constexpr int C_   = 128;
constexpr int S_   = 16384;
constexpr int NTOK = 65536; // B*V*T*S

__device__ __forceinline__ unsigned short f2bf(float f) {
    unsigned int u = __float_as_uint(f);
    unsigned int r = (u + 0x7FFFu + ((u >> 16) & 1u)) >> 16;
    return (unsigned short)r;
}
__device__ __forceinline__ float bf2f(unsigned short h) {
    return __uint_as_float(((unsigned int)h) << 16);
}
// gelu tanh-approx; tanh via exp-form (identical math, v_exp_f32 based)
__device__ __forceinline__ float gelu_tanh(float v) {
    const float k0 = 0.7978845608028654f;
    float u = k0 * (v + 0.044715f * v * v * v);
    float au = fabsf(u);
    float E = __expf(2.0f * au);
    float th = 1.0f - 2.0f / (1.0f + E);       // tanh(|u|)
    th = (u < 0.f) ? -th : th;
    return 0.5f * v * (1.0f + th);
}

// ---------------------------------------------------------------------------
// Prep: pack weights into MFMA B-fragment order, bf16. (unchanged)
// ---------------------------------------------------------------------------
__global__ __launch_bounds__(256) void prep_weights(
    const float* __restrict__ Wq, const float* __restrict__ Wkv,
    const float* __restrict__ W_ao, const float* __restrict__ W1,
    const float* __restrict__ W2, const float* __restrict__ Wout,
    unsigned short* __restrict__ Wf)
{
    int idx = blockIdx.x * 256 + threadIdx.x;
    if (idx >= 147456) return;
    int seg, off, K, N; const float* src = nullptr;
    if (idx < 49152)       { seg = 0; off = 0;      K = 128; N = 384; }
    else if (idx < 65536)  { seg = 1; off = 49152;  K = 128; N = 128; src = W_ao; }
    else if (idx < 98304)  { seg = 2; off = 65536;  K = 128; N = 256; src = W1; }
    else if (idx < 131072) { seg = 3; off = 98304;  K = 256; N = 128; src = W2; }
    else                   { seg = 4; off = 131072; K = 128; N = 128; src = Wout; }
    int local = idx - off;
    int j    = local & 7;
    int lane = (local >> 3) & 63;
    int tl   = local >> 9;
    int KB   = K >> 5;
    int kb   = tl % KB;
    int nt   = tl / KB;
    int k    = kb * 32 + ((lane >> 4) << 3) + j;
    int col  = (nt << 4) + (lane & 15);
    float v;
    if (seg == 0) v = (col < 128) ? Wq[k * 128 + col] : Wkv[k * 256 + (col - 128)];
    else          v = src[k * N + col];
    Wf[idx] = f2bf(v);
}

// ---------------------------------------------------------------------------
// Kernel A: LN1 + [q | kv] projection.  (unchanged from R6)
// ---------------------------------------------------------------------------
__global__ __launch_bounds__(256, 2) void qkv_kernel(
    const float* __restrict__ x,
    const float* __restrict__ ln1_g, const float* __restrict__ ln1_b,
    const unsigned short* __restrict__ Wf,
    const float* __restrict__ b_kv,
    float* qout, unsigned short* __restrict__ kout,
    unsigned short* __restrict__ vout)
{
    __shared__ unsigned short xet[64 * 128]; // bf16, XOR-swizzled, 16KB
    const int tile = blockIdx.x;
    const int t = threadIdx.x;

    {
        const int row = t >> 2;
        const int q4  = t & 3;
        const int tok = tile * 64 + row;
        const float* xr = x + (size_t)tok * C_ + q4 * 32;
        float v[32];
        float s0 = 0.f, s1 = 0.f;
        #pragma unroll
        for (int i = 0; i < 32; i += 4) {
            float4 f = *(const float4*)(xr + i);
            v[i] = f.x; v[i+1] = f.y; v[i+2] = f.z; v[i+3] = f.w;
            s0 += f.x + f.y + f.z + f.w;
            s1 += f.x*f.x + f.y*f.y + f.z*f.z + f.w*f.w;
        }
        s0 += __shfl_xor(s0, 1, 64); s1 += __shfl_xor(s1, 1, 64);
        s0 += __shfl_xor(s0, 2, 64); s1 += __shfl_xor(s1, 2, 64);
        const float mean = s0 * (1.0f / C_);
        const float var  = s1 * (1.0f / C_) - mean * mean;
        const float inv  = rsqrtf(var + 1e-5f);
        #pragma unroll
        for (int jj = 0; jj < 4; ++jj) {
            unsigned short tmp[8];
            #pragma unroll
            for (int j = 0; j < 8; ++j) {
                int k = q4 * 32 + jj * 8 + j;
                tmp[j] = f2bf((v[jj*8 + j] - mean) * inv * ln1_g[k] + ln1_b[k]);
            }
            int byte = row * 256 + (q4 * 32 + jj * 8) * 2;
            byte ^= (row & 7) << 4;
            *(s16x8*)((char*)xet + byte) = *(const s16x8*)tmp;
        }
    }
    __syncthreads();

    const int w = t >> 6, l = t & 63;
    const int arow = (w << 4) + (l & 15);
    s16x8 af[4];
    #pragma unroll
    for (int kb = 0; kb < 4; ++kb) {
        int byte = arow * 256 + (kb * 32 + ((l >> 4) << 3)) * 2;
        byte ^= (arow & 7) << 4;
        af[kb] = *(const s16x8*)((const char*)xet + byte);
    }
    f32x4 acc[24];
    #pragma unroll
    for (int nt = 0; nt < 24; ++nt) acc[nt] = (f32x4){0.f, 0.f, 0.f, 0.f};
    #pragma unroll
    for (int nt = 0; nt < 24; ++nt) {
        #pragma unroll
        for (int kb = 0; kb < 4; ++kb) {
            s16x8 bf = *(const s16x8*)(Wf + (size_t)((nt * 4 + kb) * 64 + l) * 8);
            acc[nt] = __builtin_amdgcn_mfma_f32_16x16x32_bf16(af[kb], bf, acc[nt], 0, 0, 0);
        }
    }
    const int r0 = (l >> 4) << 2;
    const int colb = l & 15;
    #pragma unroll
    for (int nt = 0; nt < 8; ++nt) {
        const int col = nt * 16 + colb;
        #pragma unroll
        for (int reg = 0; reg < 4; ++reg) {
            const size_t tokr = (size_t)tile * 64 + (w << 4) + r0 + reg;
            qout[tokr * 128 + col] = acc[nt][reg];
        }
    }
    #pragma unroll
    for (int i = 0; i < 8; ++i) {
        const int ch = i * 16 + colb;
        const float bk = b_kv[ch];
        const float bv = b_kv[ch + 128];
        #pragma unroll
        for (int reg = 0; reg < 4; ++reg) {
            const size_t tokr = (size_t)tile * 64 + (w << 4) + r0 + reg;
            kout[tokr * 128 + ch] = f2bf(acc[8 + i][reg] + bk);
            vout[tokr * 128 + ch] = f2bf(acc[16 + i][reg] + bv);
        }
    }
}

// ---------------------------------------------------------------------------
// Kernel B: attention, 8 lanes per token.  (unchanged from R6)
// ---------------------------------------------------------------------------
__global__ __launch_bounds__(256, 5) void attn_kernel(
    const int* __restrict__ adjc, const unsigned char* __restrict__ mask,
    const float* __restrict__ wnh,
    const float* __restrict__ qbuf,
    const unsigned short* __restrict__ kbuf,
    const unsigned short* __restrict__ vbuf,
    unsigned short* __restrict__ obuf)
{
    __shared__ unsigned int sidx[32][9];

    const int d   = blockIdx.x;
    const int xcd = d & 7, dj = d >> 3;
    const int bid = (xcd >> 1) * 512 + dj * 2 + (xcd & 1);
    const size_t base = (size_t)bid * 32;
    const int s0  = (int)(base & (S_ - 1));
    const int bvt = (int)(base >> 14);
    const int t = threadIdx.x;

    for (int i = t; i < 288; i += 256) {
        int r = i / 9, n = i - r * 9;
        int nb = adjc[(s0 + r) * 9 + n];
        unsigned int gi = (unsigned int)(bvt * S_ + nb);
        sidx[r][n] = gi | (mask[gi] ? 0x80000000u : 0u);
    }
    __syncthreads();

    const int w = t >> 6, l = t & 63;
    const int g = l >> 3, j = l & 7;
    const int r = w * 8 + g;
    const size_t tok = base + r;

    float q[16];
    {
        const float4* qp = (const float4*)(qbuf + tok * 128 + j * 16);
        #pragma unroll
        for (int i = 0; i < 4; ++i) {
            float4 f = qp[i];
            q[4*i] = f.x; q[4*i+1] = f.y; q[4*i+2] = f.z; q[4*i+3] = f.w;
        }
    }
    unsigned int gm[9];
    #pragma unroll
    for (int n = 0; n < 9; ++n) gm[n] = sidx[r][n];

    float sp[9];
    #pragma unroll
    for (int n = 0; n < 9; ++n) {
        const s16x8* kp = (const s16x8*)(kbuf +
            (size_t)(gm[n] & 0x7fffffffu) * 128 + j * 16);
        s16x8 k0 = kp[0], k1 = kp[1];
        float a = 0.f;
        #pragma unroll
        for (int i = 0; i < 8; ++i) a += q[i]     * bf2f((unsigned short)k0[i]);
        #pragma unroll
        for (int i = 0; i < 8; ++i) a += q[8 + i] * bf2f((unsigned short)k1[i]);
        sp[n] = a;
    }
    #pragma unroll
    for (int n = 0; n < 9; ++n) sp[n] += __shfl_xor(sp[n], 1, 64);

    float S[9];
    #pragma unroll
    for (int m = 0; m < 9; ++m) {
        float a = sp[m];
        #pragma unroll
        for (int n = 0; n < 9; ++n) a += sp[n] * wnh[n * 9 + m];
        a *= 0.17677669529663687f;
        S[m] = (gm[m] & 0x80000000u) ? -1e9f : a;
    }
    float mx = S[0];
    #pragma unroll
    for (int m = 1; m < 9; ++m) mx = fmaxf(mx, S[m]);
    float e[9], se = 0.f;
    #pragma unroll
    for (int m = 0; m < 9; ++m) { e[m] = __expf(S[m] - mx); se += e[m]; }
    const float inv = 1.f / se;

    float ap[9];
    #pragma unroll
    for (int n = 0; n < 9; ++n) {
        float a = e[n];
        #pragma unroll
        for (int m = 0; m < 9; ++m) a += wnh[n * 9 + m] * e[m];
        ap[n] = a * inv;
    }

    float o[16];
    #pragma unroll
    for (int i = 0; i < 16; ++i) o[i] = 0.f;
    #pragma unroll
    for (int n = 0; n < 9; ++n) {
        const s16x8* vp = (const s16x8*)(vbuf +
            (size_t)(gm[n] & 0x7fffffffu) * 128 + j * 16);
        s16x8 v0 = vp[0], v1 = vp[1];
        const float a = ap[n];
        #pragma unroll
        for (int i = 0; i < 8; ++i) o[i]     += a * bf2f((unsigned short)v0[i]);
        #pragma unroll
        for (int i = 0; i < 8; ++i) o[8 + i] += a * bf2f((unsigned short)v1[i]);
    }
    unsigned short tmp[16];
    #pragma unroll
    for (int i = 0; i < 16; ++i) tmp[i] = f2bf(o[i]);
    s16x8* op = (s16x8*)(obuf + tok * 256 + j * 16);
    op[0] = *(const s16x8*)tmp;
    op[1] = *(const s16x8*)(tmp + 8);
}

// ---------------------------------------------------------------------------
// Kernel C: fused epilogue. 32-token tile, 4 waves in a 2x2 grid:
// wave (wr = w>>1, wc = w&1) owns rows [wr*16,+16) x cols [wc*64,+64)
// (GEMM2: cols [wc*128,+128)).  Halved per-wave accumulators (no spills),
// 2048 blocks = 8/CU.  LN2 stats combined across the two col-half waves
// via LDS.  No forced low launch bound (R7 spill lesson).
// ---------------------------------------------------------------------------
__global__ __launch_bounds__(256, 2) void mlp_kernel(
    const float* __restrict__ x,
    const unsigned short* obuf,
    const unsigned short* __restrict__ Wao_f, const unsigned short* __restrict__ W1f,
    const unsigned short* __restrict__ W2f, const unsigned short* __restrict__ Woutf,
    const float* __restrict__ ln2_g, const float* __restrict__ ln2_b,
    const float* __restrict__ b1, const float* __restrict__ b2,
    const float* __restrict__ gamma,
    float* outp)
{
    __shared__ unsigned short act[8192];   // 16KB: xm/y [32][128] or h [32][256]
    __shared__ float sred[2][32][2];       // per-col-half row stats
    const int tile = blockIdx.x;
    const int t = threadIdx.x;
    const int w = t >> 6, l = t & 63;
    const int wr = w >> 1, wc = w & 1;
    const int arow = (wr << 4) + (l & 15);          // A-frag row (0..31)
    const int crow0 = (wr << 4) + ((l >> 4) << 2);  // C row base
    const int colb = l & 15;
    const size_t base = (size_t)tile * 32;

    // ---- GEMM1: ao-quadrant = o @ W_ao[:, wc*64..+64) ----
    s16x8 af[4];
    #pragma unroll
    for (int kb = 0; kb < 4; ++kb)
        af[kb] = *(const s16x8*)(obuf + (base + arow) * 256 + kb * 32 + ((l >> 4) << 3));
    f32x4 acc1[4];
    #pragma unroll
    for (int nt = 0; nt < 4; ++nt) acc1[nt] = (f32x4){0.f, 0.f, 0.f, 0.f};
    #pragma unroll
    for (int nt = 0; nt < 4; ++nt) {
        const int ntg = wc * 4 + nt;
        #pragma unroll
        for (int kb = 0; kb < 4; ++kb) {
            s16x8 bf = *(const s16x8*)(Wao_f + (size_t)((ntg * 4 + kb) * 64 + l) * 8);
            acc1[nt] = __builtin_amdgcn_mfma_f32_16x16x32_bf16(af[kb], bf, acc1[nt], 0, 0, 0);
        }
    }

    // ---- x1 = x + ao ; partial LN2 stats over this wave's 64 cols ----
    float x1v[4][4];
    float ss[4] = {0.f, 0.f, 0.f, 0.f}, s2[4] = {0.f, 0.f, 0.f, 0.f};
    #pragma unroll
    for (int nt = 0; nt < 4; ++nt) {
        const int col = wc * 64 + nt * 16 + colb;
        #pragma unroll
        for (int reg = 0; reg < 4; ++reg) {
            const size_t tokr = base + crow0 + reg;
            float xv = x[tokr * 128 + col] + acc1[nt][reg];
            x1v[nt][reg] = xv;
            ss[reg] += xv;
            s2[reg] += xv * xv;
        }
    }
    #pragma unroll
    for (int off = 1; off < 16; off <<= 1) {
        #pragma unroll
        for (int reg = 0; reg < 4; ++reg) {
            ss[reg] += __shfl_xor(ss[reg], off, 64);
            s2[reg] += __shfl_xor(s2[reg], off, 64);
        }
    }
    if (colb == 0) {
        #pragma unroll
        for (int reg = 0; reg < 4; ++reg) {
            sred[wc][crow0 + reg][0] = ss[reg];
            sred[wc][crow0 + reg][1] = s2[reg];
        }
    }
    __syncthreads();
    float mean[4], inv[4];
    #pragma unroll
    for (int reg = 0; reg < 4; ++reg) {
        const int row = crow0 + reg;
        float sum = sred[0][row][0] + sred[1][row][0];
        float sq  = sred[0][row][1] + sred[1][row][1];
        mean[reg] = sum * (1.0f / 128.f);
        float var = sq * (1.0f / 128.f) - mean[reg] * mean[reg];
        inv[reg] = rsqrtf(var + 1e-5f);
    }
    // xm -> LDS [32][128] bf16 swizzled
    #pragma unroll
    for (int nt = 0; nt < 4; ++nt) {
        const int col = wc * 64 + nt * 16 + colb;
        const float lg = ln2_g[col], lb = ln2_b[col];
        #pragma unroll
        for (int reg = 0; reg < 4; ++reg) {
            const int lrow = crow0 + reg;
            float xm = (x1v[nt][reg] - mean[reg]) * inv[reg] * lg + lb;
            int byte = lrow * 256 + col * 2;
            byte ^= (lrow & 7) << 4;
            *(unsigned short*)((char*)act + byte) = f2bf(xm);
        }
    }
    __syncthreads();

    // ---- GEMM2: h-half = xm @ W1[:, wc*128..+128) ----
    #pragma unroll
    for (int kb = 0; kb < 4; ++kb) {
        int byte = arow * 256 + (kb * 32 + ((l >> 4) << 3)) * 2;
        byte ^= (arow & 7) << 4;
        af[kb] = *(const s16x8*)((const char*)act + byte);
    }
    f32x4 acc2[8];
    #pragma unroll
    for (int nt = 0; nt < 8; ++nt) acc2[nt] = (f32x4){0.f, 0.f, 0.f, 0.f};
    #pragma unroll
    for (int nt = 0; nt < 8; ++nt) {
        const int ntg = wc * 8 + nt;
        #pragma unroll
        for (int kb = 0; kb < 4; ++kb) {
            s16x8 bf = *(const s16x8*)(W1f + (size_t)((ntg * 4 + kb) * 64 + l) * 8);
            acc2[nt] = __builtin_amdgcn_mfma_f32_16x16x32_bf16(af[kb], bf, acc2[nt], 0, 0, 0);
        }
    }
    __syncthreads();   // all xm reads done before h overwrites act
    // h -> LDS [32][256] bf16 swizzled (16KB)
    #pragma unroll
    for (int nt = 0; nt < 8; ++nt) {
        const int col2 = wc * 128 + nt * 16 + colb;
        const float bb = b1[col2];
        #pragma unroll
        for (int reg = 0; reg < 4; ++reg) {
            const int lrow = crow0 + reg;
            float hv = gelu_tanh(acc2[nt][reg] + bb);
            int byte = lrow * 512 + col2 * 2;
            byte ^= (lrow & 7) << 4;
            *(unsigned short*)((char*)act + byte) = f2bf(hv);
        }
    }
    __syncthreads();

    // ---- GEMM3: z-quadrant = h @ W2[:, wc*64..+64), K=256 ----
    f32x4 acc3[4];
    #pragma unroll
    for (int nt = 0; nt < 4; ++nt) acc3[nt] = (f32x4){0.f, 0.f, 0.f, 0.f};
    #pragma unroll
    for (int kb = 0; kb < 8; ++kb) {
        int byte = arow * 512 + (kb * 32 + ((l >> 4) << 3)) * 2;
        byte ^= (arow & 7) << 4;
        s16x8 hf = *(const s16x8*)((const char*)act + byte);
        #pragma unroll
        for (int nt = 0; nt < 4; ++nt) {
            const int ntg = wc * 4 + nt;
            s16x8 bf = *(const s16x8*)(W2f + (size_t)((ntg * 8 + kb) * 64 + l) * 8);
            acc3[nt] = __builtin_amdgcn_mfma_f32_16x16x32_bf16(hf, bf, acc3[nt], 0, 0, 0);
        }
    }
    __syncthreads();   // all h reads done before y overwrites act
    // y = x1 + gamma*(z + b2) -> LDS [32][128]
    #pragma unroll
    for (int nt = 0; nt < 4; ++nt) {
        const int col = wc * 64 + nt * 16 + colb;
        const float gm = gamma[col], bb = b2[col];
        #pragma unroll
        for (int reg = 0; reg < 4; ++reg) {
            const int lrow = crow0 + reg;
            float y = x1v[nt][reg] + gm * (acc3[nt][reg] + bb);
            int byte = lrow * 256 + col * 2;
            byte ^= (lrow & 7) << 4;
            *(unsigned short*)((char*)act + byte) = f2bf(y);
        }
    }
    __syncthreads();

    // ---- GEMM4: out-quadrant = y @ Wout[:, wc*64..+64) ----
    #pragma unroll
    for (int kb = 0; kb < 4; ++kb) {
        int byte = arow * 256 + (kb * 32 + ((l >> 4) << 3)) * 2;
        byte ^= (arow & 7) << 4;
        af[kb] = *(const s16x8*)((const char*)act + byte);
    }
    f32x4 acc4[4];
    #pragma unroll
    for (int nt = 0; nt < 4; ++nt) acc4[nt] = (f32x4){0.f, 0.f, 0.f, 0.f};
    #pragma unroll
    for (int nt = 0; nt < 4; ++nt) {
        const int ntg = wc * 4 + nt;
        #pragma unroll
        for (int kb = 0; kb < 4; ++kb) {
            s16x8 bf = *(const s16x8*)(Woutf + (size_t)((ntg * 4 + kb) * 64 + l) * 8);
            acc4[nt] = __builtin_amdgcn_mfma_f32_16x16x32_bf16(af[kb], bf, acc4[nt], 0, 0, 0);
        }
    }
    #pragma unroll
    for (int nt = 0; nt < 4; ++nt) {
        const int col = wc * 64 + nt * 16 + colb;
        #pragma unroll
        for (int reg = 0; reg < 4; ++reg) {
            const size_t tokr = base + crow0 + reg;
            outp[tokr * 128 + col] = acc4[nt][reg];
        }
    }
}

} // namespace

extern "C" void kernel_launch(void* const* d_in, const int* in_sizes, int n_in,
                              void* d_out, int out_size, void* d_ws, size_t ws_size,
                              hipStream_t stream) {
    const float* x     = (const float*)d_in[0];
    const int*   adjc  = (const int*)d_in[1];
    const unsigned char* mask = (const unsigned char*)d_in[2];
    const float* ln1_g = (const float*)d_in[3];
    const float* ln1_b = (const float*)d_in[4];
    const float* Wq    = (const float*)d_in[5];
    const float* Wkv   = (const float*)d_in[6];
    const float* b_kv  = (const float*)d_in[7];
    const float* W_nh  = (const float*)d_in[8];
    const float* W_ao  = (const float*)d_in[9];
    const float* ln2_g = (const float*)d_in[10];
    const float* ln2_b = (const float*)d_in[11];
    const float* W1    = (const float*)d_in[12];
    const float* b1    = (const float*)d_in[13];
    const float* W2    = (const float*)d_in[14];
    const float* b2    = (const float*)d_in[15];
    const float* gamma = (const float*)d_in[16];
    const float* Wout  = (const float*)d_in[17];

    // ws layout: k bf16 [0,16MiB) ; v bf16 [16,32MiB) ; Wf fragments after.
    unsigned short* kbuf = (unsigned short*)d_ws;
    unsigned short* vbuf = kbuf + (size_t)NTOK * 128;
    unsigned short* Wf   = vbuf + (size_t)NTOK * 128;
    unsigned short* Wao_f  = Wf + 49152;
    unsigned short* W1f    = Wf + 65536;
    unsigned short* W2f    = Wf + 98304;
    unsigned short* Woutf  = Wf + 131072;

    float*          qbuf = (float*)d_out;           // q fp32 full rows
    unsigned short* obuf = (unsigned short*)d_out;  // o bf16 first 256B/row

    prep_weights<<<576, 256, 0, stream>>>(Wq, Wkv, W_ao, W1, W2, Wout, Wf);
    qkv_kernel<<<NTOK / 64, 256, 0, stream>>>(x, ln1_g, ln1_b, Wf, b_kv,
                                              qbuf, kbuf, vbuf);
    attn_kernel<<<NTOK / 32, 256, 0, stream>>>(adjc, mask, W_nh,
                                               qbuf, kbuf, vbuf, obuf);
    mlp_kernel<<<NTOK / 32, 256, 0, stream>>>(x, obuf, Wao_f, W1f, W2f, Woutf,
                                              ln2_g, ln2_b, b1, b2, gamma,
                                              (float*)d_out);
}

// Round 9
// 134.192 us; speedup vs baseline: 1.4164x; 1.1760x over previous
//
#include <hip/hip_runtime.h>
#include <math.h>

namespace {

typedef float f32x4 __attribute__((ext_vector_type(4)));
typedef short s16x8 __attribute__((ext_vector_type(8)));

constexpr int C_   = 128;
constexpr int S_   = 16384;
constexpr int NTOK = 65536; // B*V*T*S

__device__ __forceinline__ unsigned short f2bf(float f) {
    unsigned int u = __float_as_uint(f);
    unsigned int r = (u + 0x7FFFu + ((u >> 16) & 1u)) >> 16;
    return (unsigned short)r;
}
__device__ __forceinline__ float bf2f(unsigned short h) {
    return __uint_as_float(((unsigned int)h) << 16);
}
// gelu tanh-approx; tanh via exp-form (identical math, v_exp_f32 based)
__device__ __forceinline__ float gelu_tanh(float v) {
    const float k0 = 0.7978845608028654f;
    float u = k0 * (v + 0.044715f * v * v * v);
    float au = fabsf(u);
    float E = __expf(2.0f * au);
    float th = 1.0f - 2.0f / (1.0f + E);       // tanh(|u|)
    th = (u < 0.f) ? -th : th;
    return 0.5f * v * (1.0f + th);
}

// ---------------------------------------------------------------------------
// Prep: pack weights into MFMA B-fragment order, bf16. (unchanged)
// ---------------------------------------------------------------------------
__global__ __launch_bounds__(256) void prep_weights(
    const float* __restrict__ Wq, const float* __restrict__ Wkv,
    const float* __restrict__ W_ao, const float* __restrict__ W1,
    const float* __restrict__ W2, const float* __restrict__ Wout,
    unsigned short* __restrict__ Wf)
{
    int idx = blockIdx.x * 256 + threadIdx.x;
    if (idx >= 147456) return;
    int seg, off, K, N; const float* src = nullptr;
    if (idx < 49152)       { seg = 0; off = 0;      K = 128; N = 384; }
    else if (idx < 65536)  { seg = 1; off = 49152;  K = 128; N = 128; src = W_ao; }
    else if (idx < 98304)  { seg = 2; off = 65536;  K = 128; N = 256; src = W1; }
    else if (idx < 131072) { seg = 3; off = 98304;  K = 256; N = 128; src = W2; }
    else                   { seg = 4; off = 131072; K = 128; N = 128; src = Wout; }
    int local = idx - off;
    int j    = local & 7;
    int lane = (local >> 3) & 63;
    int tl   = local >> 9;
    int KB   = K >> 5;
    int kb   = tl % KB;
    int nt   = tl / KB;
    int k    = kb * 32 + ((lane >> 4) << 3) + j;
    int col  = (nt << 4) + (lane & 15);
    float v;
    if (seg == 0) v = (col < 128) ? Wq[k * 128 + col] : Wkv[k * 256 + (col - 128)];
    else          v = src[k * N + col];
    Wf[idx] = f2bf(v);
}

// ---------------------------------------------------------------------------
// Kernel A: LN1 + [q | kv] projection.  (unchanged from R6/R8)
// q fp32 -> full d_out rows ; k, v bf16 -> separate ws buffers (256B rows).
// ---------------------------------------------------------------------------
__global__ __launch_bounds__(256, 2) void qkv_kernel(
    const float* __restrict__ x,
    const float* __restrict__ ln1_g, const float* __restrict__ ln1_b,
    const unsigned short* __restrict__ Wf,
    const float* __restrict__ b_kv,
    float* qout, unsigned short* __restrict__ kout,
    unsigned short* __restrict__ vout)
{
    __shared__ unsigned short xet[64 * 128]; // bf16, XOR-swizzled, 16KB
    const int tile = blockIdx.x;
    const int t = threadIdx.x;

    {
        const int row = t >> 2;
        const int q4  = t & 3;
        const int tok = tile * 64 + row;
        const float* xr = x + (size_t)tok * C_ + q4 * 32;
        float v[32];
        float s0 = 0.f, s1 = 0.f;
        #pragma unroll
        for (int i = 0; i < 32; i += 4) {
            float4 f = *(const float4*)(xr + i);
            v[i] = f.x; v[i+1] = f.y; v[i+2] = f.z; v[i+3] = f.w;
            s0 += f.x + f.y + f.z + f.w;
            s1 += f.x*f.x + f.y*f.y + f.z*f.z + f.w*f.w;
        }
        s0 += __shfl_xor(s0, 1, 64); s1 += __shfl_xor(s1, 1, 64);
        s0 += __shfl_xor(s0, 2, 64); s1 += __shfl_xor(s1, 2, 64);
        const float mean = s0 * (1.0f / C_);
        const float var  = s1 * (1.0f / C_) - mean * mean;
        const float inv  = rsqrtf(var + 1e-5f);
        #pragma unroll
        for (int jj = 0; jj < 4; ++jj) {
            unsigned short tmp[8];
            #pragma unroll
            for (int j = 0; j < 8; ++j) {
                int k = q4 * 32 + jj * 8 + j;
                tmp[j] = f2bf((v[jj*8 + j] - mean) * inv * ln1_g[k] + ln1_b[k]);
            }
            int byte = row * 256 + (q4 * 32 + jj * 8) * 2;
            byte ^= (row & 7) << 4;
            *(s16x8*)((char*)xet + byte) = *(const s16x8*)tmp;
        }
    }
    __syncthreads();

    const int w = t >> 6, l = t & 63;
    const int arow = (w << 4) + (l & 15);
    s16x8 af[4];
    #pragma unroll
    for (int kb = 0; kb < 4; ++kb) {
        int byte = arow * 256 + (kb * 32 + ((l >> 4) << 3)) * 2;
        byte ^= (arow & 7) << 4;
        af[kb] = *(const s16x8*)((const char*)xet + byte);
    }
    f32x4 acc[24];
    #pragma unroll
    for (int nt = 0; nt < 24; ++nt) acc[nt] = (f32x4){0.f, 0.f, 0.f, 0.f};
    #pragma unroll
    for (int nt = 0; nt < 24; ++nt) {
        #pragma unroll
        for (int kb = 0; kb < 4; ++kb) {
            s16x8 bf = *(const s16x8*)(Wf + (size_t)((nt * 4 + kb) * 64 + l) * 8);
            acc[nt] = __builtin_amdgcn_mfma_f32_16x16x32_bf16(af[kb], bf, acc[nt], 0, 0, 0);
        }
    }
    const int r0 = (l >> 4) << 2;
    const int colb = l & 15;
    #pragma unroll
    for (int nt = 0; nt < 8; ++nt) {
        const int col = nt * 16 + colb;
        #pragma unroll
        for (int reg = 0; reg < 4; ++reg) {
            const size_t tokr = (size_t)tile * 64 + (w << 4) + r0 + reg;
            qout[tokr * 128 + col] = acc[nt][reg];
        }
    }
    #pragma unroll
    for (int i = 0; i < 8; ++i) {
        const int ch = i * 16 + colb;
        const float bk = b_kv[ch];
        const float bv = b_kv[ch + 128];
        #pragma unroll
        for (int reg = 0; reg < 4; ++reg) {
            const size_t tokr = (size_t)tile * 64 + (w << 4) + r0 + reg;
            kout[tokr * 128 + ch] = f2bf(acc[8 + i][reg] + bk);
            vout[tokr * 128 + ch] = f2bf(acc[16 + i][reg] + bv);
        }
    }
}

// ---------------------------------------------------------------------------
// Kernel B: fused attention + epilogue.  32-token tile, 256 threads, 2048
// blocks (XCD-swizzled).
// Attn phase (R6-proven layout): thread t -> token r=t>>3, chunk j=t&7
// (head j>>1).  Fully-coalesced 256B k/v row gathers; one shfl_xor(1) per
// neighbor for the per-head dot; score-space mix + softmax + weight-space
// mix in-register; o written DIRECTLY into swizzled act LDS (no HBM trip).
// MLP phase (R8-proven 2x2 wave grid): GEMM1 A-frags from act LDS, then
// x1/LN2 -> GEMM2 gelu -> GEMM3 -> GEMM4 -> out fp32 to d_out.
// ---------------------------------------------------------------------------
__global__ __launch_bounds__(256, 2) void attn_mlp_kernel(
    const float* __restrict__ x,
    const int* __restrict__ adjc, const unsigned char* __restrict__ mask,
    const float* __restrict__ wnh,
    const float* __restrict__ qbuf,                 // aliases d_out (fp32 q)
    const unsigned short* __restrict__ kbuf,
    const unsigned short* __restrict__ vbuf,
    const unsigned short* __restrict__ Wao_f, const unsigned short* __restrict__ W1f,
    const unsigned short* __restrict__ W2f, const unsigned short* __restrict__ Woutf,
    const float* __restrict__ ln2_g, const float* __restrict__ ln2_b,
    const float* __restrict__ b1, const float* __restrict__ b2,
    const float* __restrict__ gamma,
    float* outp)                                    // aliases d_out
{
    __shared__ unsigned short act[8192];   // 16KB: o/xm/y [32][128] or h [32][256]
    __shared__ float sred[2][32][2];       // per-col-half LN2 row stats
    __shared__ unsigned int sidx[32][9];   // gathered row index | mask<<31

    // bijective XCD swizzle: 2048 blocks, 512 per slab-pair
    const int d   = blockIdx.x;
    const int xcd = d & 7, dj = d >> 3;
    const int bid = (xcd >> 1) * 512 + dj * 2 + (xcd & 1);
    const size_t base = (size_t)bid * 32;
    const int s0  = (int)(base & (S_ - 1));
    const int bvt = (int)(base >> 14);
    const int t = threadIdx.x;

    for (int i = t; i < 288; i += 256) {
        int r = i / 9, n = i - r * 9;
        int nb = adjc[(s0 + r) * 9 + n];
        unsigned int gi = (unsigned int)(bvt * S_ + nb);
        sidx[r][n] = gi | (mask[gi] ? 0x80000000u : 0u);
    }
    __syncthreads();

    // ================= attention phase =================
    {
        const int r = t >> 3, j = t & 7;   // token-in-tile, channel chunk
        const size_t tok = base + r;

        float q[16];
        {
            const float4* qp = (const float4*)(qbuf + tok * 128 + j * 16);
            #pragma unroll
            for (int i = 0; i < 4; ++i) {
                float4 f = qp[i];
                q[4*i] = f.x; q[4*i+1] = f.y; q[4*i+2] = f.z; q[4*i+3] = f.w;
            }
        }
        unsigned int gm[9];
        #pragma unroll
        for (int n = 0; n < 9; ++n) gm[n] = sidx[r][n];

        float sp[9];
        #pragma unroll
        for (int n = 0; n < 9; ++n) {
            const s16x8* kp = (const s16x8*)(kbuf +
                (size_t)(gm[n] & 0x7fffffffu) * 128 + j * 16);
            s16x8 k0 = kp[0], k1 = kp[1];
            float a = 0.f;
            #pragma unroll
            for (int i = 0; i < 8; ++i) a += q[i]     * bf2f((unsigned short)k0[i]);
            #pragma unroll
            for (int i = 0; i < 8; ++i) a += q[8 + i] * bf2f((unsigned short)k1[i]);
            sp[n] = a;
        }
        #pragma unroll
        for (int n = 0; n < 9; ++n) sp[n] += __shfl_xor(sp[n], 1, 64);

        float S[9];
        #pragma unroll
        for (int m = 0; m < 9; ++m) {
            float a = sp[m];   // identity part of M = I + W_nh
            #pragma unroll
            for (int n = 0; n < 9; ++n) a += sp[n] * wnh[n * 9 + m];
            a *= 0.17677669529663687f;
            S[m] = (gm[m] & 0x80000000u) ? -1e9f : a;
        }
        float mx = S[0];
        #pragma unroll
        for (int m = 1; m < 9; ++m) mx = fmaxf(mx, S[m]);
        float e[9], se = 0.f;
        #pragma unroll
        for (int m = 0; m < 9; ++m) { e[m] = __expf(S[m] - mx); se += e[m]; }
        const float inv = 1.f / se;

        float ap[9];
        #pragma unroll
        for (int n = 0; n < 9; ++n) {
            float a = e[n];
            #pragma unroll
            for (int m = 0; m < 9; ++m) a += wnh[n * 9 + m] * e[m];
            ap[n] = a * inv;
        }

        float o[16];
        #pragma unroll
        for (int i = 0; i < 16; ++i) o[i] = 0.f;
        #pragma unroll
        for (int n = 0; n < 9; ++n) {
            const s16x8* vp = (const s16x8*)(vbuf +
                (size_t)(gm[n] & 0x7fffffffu) * 128 + j * 16);
            s16x8 v0 = vp[0], v1 = vp[1];
            const float a = ap[n];
            #pragma unroll
            for (int i = 0; i < 8; ++i) o[i]     += a * bf2f((unsigned short)v0[i]);
            #pragma unroll
            for (int i = 0; i < 8; ++i) o[8 + i] += a * bf2f((unsigned short)v1[i]);
        }
        // o -> act LDS (bf16, swizzled [32][128] layout)
        unsigned short tmp[16];
        #pragma unroll
        for (int i = 0; i < 16; ++i) tmp[i] = f2bf(o[i]);
        int b0 = (r * 256 + j * 32) ^ ((r & 7) << 4);
        int b1_ = (r * 256 + j * 32 + 16) ^ ((r & 7) << 4);
        *(s16x8*)((char*)act + b0)  = *(const s16x8*)tmp;
        *(s16x8*)((char*)act + b1_) = *(const s16x8*)(tmp + 8);
    }
    __syncthreads();

    // ================= MLP phase (R8 2x2 wave grid) =================
    const int w = t >> 6, l = t & 63;
    const int wr = w >> 1, wc = w & 1;
    const int arow = (wr << 4) + (l & 15);
    const int crow0 = (wr << 4) + ((l >> 4) << 2);
    const int colb = l & 15;

    // ---- GEMM1: ao-quadrant = o @ W_ao[:, wc*64..+64), A from act LDS ----
    s16x8 af[4];
    #pragma unroll
    for (int kb = 0; kb < 4; ++kb) {
        int byte = arow * 256 + (kb * 32 + ((l >> 4) << 3)) * 2;
        byte ^= (arow & 7) << 4;
        af[kb] = *(const s16x8*)((const char*)act + byte);
    }
    f32x4 acc1[4];
    #pragma unroll
    for (int nt = 0; nt < 4; ++nt) acc1[nt] = (f32x4){0.f, 0.f, 0.f, 0.f};
    #pragma unroll
    for (int nt = 0; nt < 4; ++nt) {
        const int ntg = wc * 4 + nt;
        #pragma unroll
        for (int kb = 0; kb < 4; ++kb) {
            s16x8 bf = *(const s16x8*)(Wao_f + (size_t)((ntg * 4 + kb) * 64 + l) * 8);
            acc1[nt] = __builtin_amdgcn_mfma_f32_16x16x32_bf16(af[kb], bf, acc1[nt], 0, 0, 0);
        }
    }

    // ---- x1 = x + ao ; partial LN2 stats over this wave's 64 cols ----
    float x1v[4][4];
    float ss[4] = {0.f, 0.f, 0.f, 0.f}, s2[4] = {0.f, 0.f, 0.f, 0.f};
    #pragma unroll
    for (int nt = 0; nt < 4; ++nt) {
        const int col = wc * 64 + nt * 16 + colb;
        #pragma unroll
        for (int reg = 0; reg < 4; ++reg) {
            const size_t tokr = base + crow0 + reg;
            float xv = x[tokr * 128 + col] + acc1[nt][reg];
            x1v[nt][reg] = xv;
            ss[reg] += xv;
            s2[reg] += xv * xv;
        }
    }
    #pragma unroll
    for (int off = 1; off < 16; off <<= 1) {
        #pragma unroll
        for (int reg = 0; reg < 4; ++reg) {
            ss[reg] += __shfl_xor(ss[reg], off, 64);
            s2[reg] += __shfl_xor(s2[reg], off, 64);
        }
    }
    if (colb == 0) {
        #pragma unroll
        for (int reg = 0; reg < 4; ++reg) {
            sred[wc][crow0 + reg][0] = ss[reg];
            sred[wc][crow0 + reg][1] = s2[reg];
        }
    }
    __syncthreads();
    float mean[4], inv[4];
    #pragma unroll
    for (int reg = 0; reg < 4; ++reg) {
        const int row = crow0 + reg;
        float sum = sred[0][row][0] + sred[1][row][0];
        float sq  = sred[0][row][1] + sred[1][row][1];
        mean[reg] = sum * (1.0f / 128.f);
        float var = sq * (1.0f / 128.f) - mean[reg] * mean[reg];
        inv[reg] = rsqrtf(var + 1e-5f);
    }
    __syncthreads();   // all GEMM1 A-frag reads of act done before xm overwrite
    #pragma unroll
    for (int nt = 0; nt < 4; ++nt) {
        const int col = wc * 64 + nt * 16 + colb;
        const float lg = ln2_g[col], lb = ln2_b[col];
        #pragma unroll
        for (int reg = 0; reg < 4; ++reg) {
            const int lrow = crow0 + reg;
            float xm = (x1v[nt][reg] - mean[reg]) * inv[reg] * lg + lb;
            int byte = lrow * 256 + col * 2;
            byte ^= (lrow & 7) << 4;
            *(unsigned short*)((char*)act + byte) = f2bf(xm);
        }
    }
    __syncthreads();

    // ---- GEMM2: h-half = xm @ W1[:, wc*128..+128) ----
    #pragma unroll
    for (int kb = 0; kb < 4; ++kb) {
        int byte = arow * 256 + (kb * 32 + ((l >> 4) << 3)) * 2;
        byte ^= (arow & 7) << 4;
        af[kb] = *(const s16x8*)((const char*)act + byte);
    }
    f32x4 acc2[8];
    #pragma unroll
    for (int nt = 0; nt < 8; ++nt) acc2[nt] = (f32x4){0.f, 0.f, 0.f, 0.f};
    #pragma unroll
    for (int nt = 0; nt < 8; ++nt) {
        const int ntg = wc * 8 + nt;
        #pragma unroll
        for (int kb = 0; kb < 4; ++kb) {
            s16x8 bf = *(const s16x8*)(W1f + (size_t)((ntg * 4 + kb) * 64 + l) * 8);
            acc2[nt] = __builtin_amdgcn_mfma_f32_16x16x32_bf16(af[kb], bf, acc2[nt], 0, 0, 0);
        }
    }
    __syncthreads();   // all xm reads done before h overwrites act
    #pragma unroll
    for (int nt = 0; nt < 8; ++nt) {
        const int col2 = wc * 128 + nt * 16 + colb;
        const float bb = b1[col2];
        #pragma unroll
        for (int reg = 0; reg < 4; ++reg) {
            const int lrow = crow0 + reg;
            float hv = gelu_tanh(acc2[nt][reg] + bb);
            int byte = lrow * 512 + col2 * 2;
            byte ^= (lrow & 7) << 4;
            *(unsigned short*)((char*)act + byte) = f2bf(hv);
        }
    }
    __syncthreads();

    // ---- GEMM3: z-quadrant = h @ W2[:, wc*64..+64), K=256 ----
    f32x4 acc3[4];
    #pragma unroll
    for (int nt = 0; nt < 4; ++nt) acc3[nt] = (f32x4){0.f, 0.f, 0.f, 0.f};
    #pragma unroll
    for (int kb = 0; kb < 8; ++kb) {
        int byte = arow * 512 + (kb * 32 + ((l >> 4) << 3)) * 2;
        byte ^= (arow & 7) << 4;
        s16x8 hf = *(const s16x8*)((const char*)act + byte);
        #pragma unroll
        for (int nt = 0; nt < 4; ++nt) {
            const int ntg = wc * 4 + nt;
            s16x8 bf = *(const s16x8*)(W2f + (size_t)((ntg * 8 + kb) * 64 + l) * 8);
            acc3[nt] = __builtin_amdgcn_mfma_f32_16x16x32_bf16(hf, bf, acc3[nt], 0, 0, 0);
        }
    }
    __syncthreads();   // all h reads done before y overwrites act
    #pragma unroll
    for (int nt = 0; nt < 4; ++nt) {
        const int col = wc * 64 + nt * 16 + colb;
        const float gm = gamma[col], bb = b2[col];
        #pragma unroll
        for (int reg = 0; reg < 4; ++reg) {
            const int lrow = crow0 + reg;
            float y = x1v[nt][reg] + gm * (acc3[nt][reg] + bb);
            int byte = lrow * 256 + col * 2;
            byte ^= (lrow & 7) << 4;
            *(unsigned short*)((char*)act + byte) = f2bf(y);
        }
    }
    __syncthreads();

    // ---- GEMM4: out-quadrant = y @ Wout[:, wc*64..+64) ----
    #pragma unroll
    for (int kb = 0; kb < 4; ++kb) {
        int byte = arow * 256 + (kb * 32 + ((l >> 4) << 3)) * 2;
        byte ^= (arow & 7) << 4;
        af[kb] = *(const s16x8*)((const char*)act + byte);
    }
    f32x4 acc4[4];
    #pragma unroll
    for (int nt = 0; nt < 4; ++nt) acc4[nt] = (f32x4){0.f, 0.f, 0.f, 0.f};
    #pragma unroll
    for (int nt = 0; nt < 4; ++nt) {
        const int ntg = wc * 4 + nt;
        #pragma unroll
        for (int kb = 0; kb < 4; ++kb) {
            s16x8 bf = *(const s16x8*)(Woutf + (size_t)((ntg * 4 + kb) * 64 + l) * 8);
            acc4[nt] = __builtin_amdgcn_mfma_f32_16x16x32_bf16(af[kb], bf, acc4[nt], 0, 0, 0);
        }
    }
    #pragma unroll
    for (int nt = 0; nt < 4; ++nt) {
        const int col = wc * 64 + nt * 16 + colb;
        #pragma unroll
        for (int reg = 0; reg < 4; ++reg) {
            const size_t tokr = base + crow0 + reg;
            outp[tokr * 128 + col] = acc4[nt][reg];
        }
    }
}

} // namespace

extern "C" void kernel_launch(void* const* d_in, const int* in_sizes, int n_in,
                              void* d_out, int out_size, void* d_ws, size_t ws_size,
                              hipStream_t stream) {
    const float* x     = (const float*)d_in[0];
    const int*   adjc  = (const int*)d_in[1];
    const unsigned char* mask = (const unsigned char*)d_in[2];
    const float* ln1_g = (const float*)d_in[3];
    const float* ln1_b = (const float*)d_in[4];
    const float* Wq    = (const float*)d_in[5];
    const float* Wkv   = (const float*)d_in[6];
    const float* b_kv  = (const float*)d_in[7];
    const float* W_nh  = (const float*)d_in[8];
    const float* W_ao  = (const float*)d_in[9];
    const float* ln2_g = (const float*)d_in[10];
    const float* ln2_b = (const float*)d_in[11];
    const float* W1    = (const float*)d_in[12];
    const float* b1    = (const float*)d_in[13];
    const float* W2    = (const float*)d_in[14];
    const float* b2    = (const float*)d_in[15];
    const float* gamma = (const float*)d_in[16];
    const float* Wout  = (const float*)d_in[17];

    // ws layout: k bf16 [0,16MiB) ; v bf16 [16,32MiB) ; Wf fragments after.
    unsigned short* kbuf = (unsigned short*)d_ws;
    unsigned short* vbuf = kbuf + (size_t)NTOK * 128;
    unsigned short* Wf   = vbuf + (size_t)NTOK * 128;
    unsigned short* Wao_f  = Wf + 49152;
    unsigned short* W1f    = Wf + 65536;
    unsigned short* W2f    = Wf + 98304;
    unsigned short* Woutf  = Wf + 131072;

    float* qbuf = (float*)d_out;   // q fp32 full rows; final out overwrites

    prep_weights<<<576, 256, 0, stream>>>(Wq, Wkv, W_ao, W1, W2, Wout, Wf);
    qkv_kernel<<<NTOK / 64, 256, 0, stream>>>(x, ln1_g, ln1_b, Wf, b_kv,
                                              qbuf, kbuf, vbuf);
    attn_mlp_kernel<<<NTOK / 32, 256, 0, stream>>>(x, adjc, mask, W_nh,
                                                   qbuf, kbuf, vbuf,
                                                   Wao_f, W1f, W2f, Woutf,
                                                   ln2_g, ln2_b, b1, b2, gamma,
                                                   (float*)d_out);
}